// Round 4
// baseline (674.096 us; speedup 1.0000x reference)
//
#include <hip/hip_runtime.h>
#include <hip/hip_bf16.h>
#include <stdint.h>

// Problem constants
#define B_    4
#define S_    4096
#define DIM_  2048
#define H_    16
#define HD_   128
#define M_    (B_ * S_)     // 16384 rows
#define K_    DIM_          // 2048
#define N_    (3 * DIM_)    // 6144 (q|k|v concatenated)

typedef __attribute__((ext_vector_type(8)))  short bf16x8;
typedef __attribute__((ext_vector_type(16))) float f32x16;

// ---------------------------------------------------------------------------
// Kernel 1: X fp32 -> bf16
// ---------------------------------------------------------------------------
__global__ void cvt_x_kernel(const float* __restrict__ X,
                             __hip_bfloat16* __restrict__ Xb) {
    size_t i = ((size_t)blockIdx.x * 256 + threadIdx.x) * 8;
    float4 a = *reinterpret_cast<const float4*>(X + i);
    float4 b = *reinterpret_cast<const float4*>(X + i + 4);
    union { __hip_bfloat16 h[8]; uint4 u; } o;
    o.h[0] = __float2bfloat16(a.x);
    o.h[1] = __float2bfloat16(a.y);
    o.h[2] = __float2bfloat16(a.z);
    o.h[3] = __float2bfloat16(a.w);
    o.h[4] = __float2bfloat16(b.x);
    o.h[5] = __float2bfloat16(b.y);
    o.h[6] = __float2bfloat16(b.z);
    o.h[7] = __float2bfloat16(b.w);
    *reinterpret_cast<uint4*>(Xb + i) = o.u;
}

// ---------------------------------------------------------------------------
// Kernel 2: Wt[n][k] = W_sel[k][n] cast to bf16  (B^T layout)
// ---------------------------------------------------------------------------
__global__ void cvt_w_kernel(const float* __restrict__ Wq,
                             const float* __restrict__ Wk,
                             const float* __restrict__ Wv,
                             __hip_bfloat16* __restrict__ Wt) {
    __shared__ float tile[32][33];
    int w = blockIdx.z;
    const float* W = (w == 0) ? Wq : (w == 1) ? Wk : Wv;
    int n0 = blockIdx.x * 32;
    int k0 = blockIdx.y * 32;
    int tx = threadIdx.x, ty = threadIdx.y;
#pragma unroll
    for (int r = 0; r < 4; ++r) {
        int k = k0 + ty + r * 8;
        tile[ty + r * 8][tx] = W[(size_t)k * DIM_ + n0 + tx];
    }
    __syncthreads();
#pragma unroll
    for (int r = 0; r < 4; ++r) {
        int n = n0 + ty + r * 8;
        Wt[(size_t)(w * DIM_ + n) * K_ + k0 + tx] =
            __float2bfloat16(tile[tx][ty + r * 8]);
    }
}

// ---------------------------------------------------------------------------
// Kernel 3: 256x256 8-phase bf16 GEMM, 32x32x16 MFMA + fused RoPE epilogue
// 8 waves (2M x 4N), BK=64, compile-time double-buffer, granule-XOR swizzle,
// one half-tile staged per phase, vmcnt(4) at phases 4/8, setprio on MFMA,
// lgkmcnt(0) AFTER the MFMA cluster (compiler fine-grains the pre-MFMA waits).
// ---------------------------------------------------------------------------
#define BM 256
#define BN 256
#define BK 64
#define NT (K_ / BK)    // 32
#define NU (NT / 2)     // 16 iterations, 2 K-tiles each

#define BAR()      asm volatile("s_barrier" ::: "memory")
#define LGKM0()    asm volatile("s_waitcnt lgkmcnt(0)" ::: "memory")
#define WAIT_VM(n) asm volatile("s_waitcnt vmcnt(" #n ")" ::: "memory")

__global__ __launch_bounds__(512, 1) void gemm_rope_kernel(
    const __hip_bfloat16* __restrict__ Xb,   // [M_][K_]
    const __hip_bfloat16* __restrict__ Wt,   // [N_][K_]
    const float* __restrict__ fcos,          // [S_][HD_]
    const float* __restrict__ fsin,          // [S_][HD_]
    float* __restrict__ out)                 // 3 regions of [M_][DIM_]
{
    __shared__ __hip_bfloat16 As[2][BM * BK];   // 2 x 32 KB
    __shared__ __hip_bfloat16 Bs[2][BN * BK];   // 2 x 32 KB

    // T1: XCD-aware bijective swizzle (grid = 1536, 1536 % 8 == 0)
    const int nbn = N_ / BN;                 // 24
    int bid = blockIdx.x;
    int cpx = gridDim.x >> 3;
    int swz = (bid & 7) * cpx + (bid >> 3);
    int tm = swz / nbn, tn = swz % nbn;
    int m0 = tm * BM, n0 = tn * BN;

    int tid  = threadIdx.x;
    int lane = tid & 63;
    int w    = tid >> 6;                     // 0..7
    int wr   = w >> 2;                       // 0..1  row half (128 rows)
    int wc   = w & 3;                        // 0..3  col quarter (64 cols)

    // staging lane decomposition: 8 rows x 8 granules(16B) per wave-issue
    int rl   = lane >> 3;                    // row within 8
    int gsw  = ((lane & 7) ^ rl) * 8;        // pre-swizzled source col (elems)
    int lcol = (lane & 7) * 8;               // linear LDS col (elems)

    // fragment-read constants (32x32x16: row/col = lane&31, k-half = lane>>5)
    int l31 = lane & 31;
    int l1  = lane >> 5;                     // k-granule half

#define STAGE_A(t, bb, r) do {                                                 \
        const __hip_bfloat16* _s = Xb + (size_t)(m0 + (r) * 64 + w * 8 + rl) * K_ \
                                      + (t) * BK + gsw;                        \
        __hip_bfloat16* _d = &As[bb][((r) * 64 + w * 8 + rl) * BK + lcol];     \
        __builtin_amdgcn_global_load_lds(                                      \
            (const __attribute__((address_space(1))) void*)_s,                 \
            (__attribute__((address_space(3))) void*)_d, 16, 0, 0);            \
    } while (0)

#define STAGE_B(t, bb, r) do {                                                 \
        const __hip_bfloat16* _s = Wt + (size_t)(n0 + (r) * 64 + w * 8 + rl) * K_ \
                                      + (t) * BK + gsw;                        \
        __hip_bfloat16* _d = &Bs[bb][((r) * 64 + w * 8 + rl) * BK + lcol];     \
        __builtin_amdgcn_global_load_lds(                                      \
            (const __attribute__((address_space(1))) void*)_s,                 \
            (__attribute__((address_space(3))) void*)_d, 16, 0, 0);            \
    } while (0)

    f32x16 acc[4][2] = {};                   // [ib][jb] 32x32 tiles
    bf16x8 a[2][4];                          // A frags: [ii][kk] (2 ib live)
    bf16x8 b[2][4];                          // B frags: [jb][kk] (both jb live)

    // LDS read: row r, k-granule g stored at byte col ((g ^ (r&7))*16)
#define LDA(bb, qi) do {                                                       \
        _Pragma("unroll")                                                      \
        for (int ii = 0; ii < 2; ++ii) {                                       \
            int _row = wr * 128 + ((qi) * 2 + ii) * 32 + l31;                  \
            int _s7  = _row & 7;                                               \
            _Pragma("unroll")                                                  \
            for (int kk = 0; kk < 4; ++kk) {                                   \
                int _g = (kk * 2 + l1) ^ _s7;                                  \
                a[ii][kk] = *reinterpret_cast<const bf16x8*>(                  \
                    &As[bb][_row * BK + _g * 8]);                              \
            }                                                                  \
        }                                                                      \
    } while (0)

#define LDB(bb, qj) do {                                                       \
        int _row = wc * 64 + (qj) * 32 + l31;                                  \
        int _s7  = _row & 7;                                                   \
        _Pragma("unroll")                                                      \
        for (int kk = 0; kk < 4; ++kk) {                                       \
            int _g = (kk * 2 + l1) ^ _s7;                                      \
            b[qj][kk] = *reinterpret_cast<const bf16x8*>(                      \
                &Bs[bb][_row * BK + _g * 8]);                                  \
        }                                                                      \
    } while (0)

#define MFMA_Q(qi, qj) do {                                                    \
        __builtin_amdgcn_s_setprio(1);                                         \
        _Pragma("unroll")                                                      \
        for (int ii = 0; ii < 2; ++ii)                                         \
        _Pragma("unroll")                                                      \
        for (int kk = 0; kk < 4; ++kk)                                         \
            acc[(qi) * 2 + ii][qj] = __builtin_amdgcn_mfma_f32_32x32x16_bf16(  \
                a[ii][kk], b[qj][kk], acc[(qi) * 2 + ii][qj], 0, 0, 0);        \
        __builtin_amdgcn_s_setprio(0);                                         \
    } while (0)

    // -------- prologue: A(0)->buf0, B(0)->buf0, B(1)->buf1 ------------------
#pragma unroll
    for (int r = 0; r < 4; ++r) STAGE_A(0, 0, r);
#pragma unroll
    for (int r = 0; r < 4; ++r) STAGE_B(0, 0, r);
#pragma unroll
    for (int r = 0; r < 4; ++r) STAGE_B(1, 1, r);
    WAIT_VM(4);                              // A(0),B(0) landed; B(1) in flight
    BAR();

    // -------- main loop: 8 phases / 2 K-tiles (staging schedule as R3) ------
    for (int u = 0; u < NU; ++u) {
        int T0 = 2 * u, T1 = 2 * u + 1;
        bool last = (u == NU - 1);
        // ph1: T0 quad (0,0)
        LDA(0, 0); LDB(0, 0);
        STAGE_A(T1, 1, 0); STAGE_A(T1, 1, 1);
        BAR();
        MFMA_Q(0, 0);
        LGKM0();
        BAR();
        // ph2: T0 quad (0,1)
        LDB(0, 1);
        STAGE_A(T1, 1, 2); STAGE_A(T1, 1, 3);
        BAR();
        MFMA_Q(0, 1);
        LGKM0();
        BAR();
        // ph3: T0 quad (1,0)  (b[0] still live)
        LDA(0, 1);
        if (!last) { STAGE_B(T0 + 2, 0, 0); STAGE_B(T0 + 2, 0, 1); }
        BAR();
        MFMA_Q(1, 0);
        LGKM0();
        BAR();
        // ph4: T0 quad (1,1)
        if (!last) { STAGE_A(T0 + 2, 0, 0); STAGE_A(T0 + 2, 0, 1); }
        BAR();
        MFMA_Q(1, 1);
        if (last) { WAIT_VM(0); } else { WAIT_VM(4); }
        BAR();
        // ph5: T1 quad (0,0)
        LDA(1, 0); LDB(1, 0);
        if (!last) { STAGE_A(T0 + 2, 0, 2); STAGE_A(T0 + 2, 0, 3); }
        BAR();
        MFMA_Q(0, 0);
        LGKM0();
        BAR();
        // ph6: T1 quad (0,1)
        LDB(1, 1);
        if (!last) { STAGE_B(T0 + 2, 0, 2); STAGE_B(T0 + 2, 0, 3); }
        BAR();
        MFMA_Q(0, 1);
        LGKM0();
        BAR();
        // ph7: T1 quad (1,0)
        LDA(1, 1);
        if (!last) { STAGE_B(T1 + 2, 1, 0); STAGE_B(T1 + 2, 1, 1); }
        BAR();
        MFMA_Q(1, 0);
        LGKM0();
        BAR();
        // ph8: T1 quad (1,1)
        if (!last) { STAGE_B(T1 + 2, 1, 2); STAGE_B(T1 + 2, 1, 3); }
        BAR();
        MFMA_Q(1, 1);
        if (!last) { WAIT_VM(4); }
        BAR();
    }

    // -------- epilogue: RoPE + store ----------------------------------------
    // 32x32 C/D: col = lane&31, row = (reg&3) + 8*(reg>>2) + 4*(lane>>5)
#pragma unroll
    for (int ib = 0; ib < 4; ++ib)
#pragma unroll
    for (int jb = 0; jb < 2; ++jb) {
        int n = n0 + wc * 64 + jb * 32 + l31;
        int region = n >> 11;                // 0=q,1=k,2=v
        int cc = n & (DIM_ - 1);
        int d  = cc & (HD_ - 1);
#pragma unroll
        for (int reg = 0; reg < 16; ++reg) {
            int m = m0 + wr * 128 + ib * 32 + (reg & 3) + 8 * (reg >> 2) + 4 * l1;
            int s = m & (S_ - 1);
            float g  = acc[ib][jb][reg];
            float gp = __shfl_xor(g, 1, 64); // interleaved pair partner (col^1)
            float o;
            if (region < 2) {
                float cv = fcos[s * HD_ + d];
                float sv = fsin[s * HD_ + d];
                o = g * cv + ((cc & 1) ? gp * sv : -gp * sv);
            } else {
                o = g;
            }
            out[(size_t)region * M_ * DIM_ + (size_t)m * DIM_ + cc] = o;
        }
    }
#undef STAGE_A
#undef STAGE_B
#undef LDA
#undef LDB
#undef MFMA_Q
}

// ---------------------------------------------------------------------------
extern "C" void kernel_launch(void* const* d_in, const int* in_sizes, int n_in,
                              void* d_out, int out_size, void* d_ws, size_t ws_size,
                              hipStream_t stream) {
    const float* X    = (const float*)d_in[0];
    const float* fcos = (const float*)d_in[1];
    const float* fsin = (const float*)d_in[2];
    // d_in[3] = attention_mask (all ones, unused by the reference math)
    const float* Wq   = (const float*)d_in[4];
    const float* Wk   = (const float*)d_in[5];
    const float* Wv   = (const float*)d_in[6];
    float* out = (float*)d_out;

    __hip_bfloat16* Xb  = (__hip_bfloat16*)d_ws;
    __hip_bfloat16* Wtp = Xb + (size_t)M_ * K_;

    {
        int threads = 256;
        int blocks = (M_ * K_) / (threads * 8);   // 16384
        cvt_x_kernel<<<blocks, threads, 0, stream>>>(X, Xb);
    }
    {
        dim3 grid(DIM_ / 32, DIM_ / 32, 3);
        dim3 block(32, 8);
        cvt_w_kernel<<<grid, block, 0, stream>>>(Wq, Wk, Wv, Wtp);
    }
    {
        int blocks = (M_ / BM) * (N_ / BN);       // 64 * 24 = 1536
        gemm_rope_kernel<<<blocks, 512, 0, stream>>>(Xb, Wtp, fcos, fsin, out);
    }
}

// Round 5
// 537.877 us; speedup vs baseline: 1.2533x; 1.2533x over previous
//
#include <hip/hip_runtime.h>
#include <hip/hip_bf16.h>
#include <stdint.h>

// Problem constants
#define B_    4
#define S_    4096
#define DIM_  2048
#define H_    16
#define HD_   128
#define M_    (B_ * S_)     // 16384 rows
#define K_    DIM_          // 2048
#define N_    (3 * DIM_)    // 6144 (q|k|v concatenated)

typedef __attribute__((ext_vector_type(8))) short bf16x8;
typedef __attribute__((ext_vector_type(4))) float f32x4;

// ---------------------------------------------------------------------------
// Kernel 1: X fp32 -> bf16
// ---------------------------------------------------------------------------
__global__ void cvt_x_kernel(const float* __restrict__ X,
                             __hip_bfloat16* __restrict__ Xb) {
    size_t i = ((size_t)blockIdx.x * 256 + threadIdx.x) * 8;
    float4 a = *reinterpret_cast<const float4*>(X + i);
    float4 b = *reinterpret_cast<const float4*>(X + i + 4);
    union { __hip_bfloat16 h[8]; uint4 u; } o;
    o.h[0] = __float2bfloat16(a.x);
    o.h[1] = __float2bfloat16(a.y);
    o.h[2] = __float2bfloat16(a.z);
    o.h[3] = __float2bfloat16(a.w);
    o.h[4] = __float2bfloat16(b.x);
    o.h[5] = __float2bfloat16(b.y);
    o.h[6] = __float2bfloat16(b.z);
    o.h[7] = __float2bfloat16(b.w);
    *reinterpret_cast<uint4*>(Xb + i) = o.u;
}

// ---------------------------------------------------------------------------
// Kernel 2: Wt[n][k] = W_sel[k][n] cast to bf16  (B^T layout)
// ---------------------------------------------------------------------------
__global__ void cvt_w_kernel(const float* __restrict__ Wq,
                             const float* __restrict__ Wk,
                             const float* __restrict__ Wv,
                             __hip_bfloat16* __restrict__ Wt) {
    __shared__ float tile[32][33];
    int w = blockIdx.z;
    const float* W = (w == 0) ? Wq : (w == 1) ? Wk : Wv;
    int n0 = blockIdx.x * 32;
    int k0 = blockIdx.y * 32;
    int tx = threadIdx.x, ty = threadIdx.y;
#pragma unroll
    for (int r = 0; r < 4; ++r) {
        int k = k0 + ty + r * 8;
        tile[ty + r * 8][tx] = W[(size_t)k * DIM_ + n0 + tx];
    }
    __syncthreads();
#pragma unroll
    for (int r = 0; r < 4; ++r) {
        int n = n0 + ty + r * 8;
        Wt[(size_t)(w * DIM_ + n) * K_ + k0 + tx] =
            __float2bfloat16(tile[tx][ty + r * 8]);
    }
}

// ---------------------------------------------------------------------------
// Kernel 3: 256x256 8-phase bf16 GEMM (R3 structure, 16x16x32 MFMA) + RoPE
// Changes vs R3: (a) XCD L2-blocking remap — each XCD owns a 3-wide tn band
// so its B working set (3 MB) stays L2-resident; (b) nontemporal C stores.
// ---------------------------------------------------------------------------
#define BM 256
#define BN 256
#define BK 64
#define NT (K_ / BK)    // 32
#define NU (NT / 2)     // 16 iterations, 2 K-tiles each

#define BAR()      asm volatile("s_barrier" ::: "memory")
#define LGKM0()    asm volatile("s_waitcnt lgkmcnt(0)" ::: "memory")
#define LGKM8()    asm volatile("s_waitcnt lgkmcnt(8)" ::: "memory")
#define WAIT_VM(n) asm volatile("s_waitcnt vmcnt(" #n ")" ::: "memory")

__global__ __launch_bounds__(512, 1) void gemm_rope_kernel(
    const __hip_bfloat16* __restrict__ Xb,   // [M_][K_]
    const __hip_bfloat16* __restrict__ Wt,   // [N_][K_]
    const float* __restrict__ fcos,          // [S_][HD_]
    const float* __restrict__ fsin,          // [S_][HD_]
    float* __restrict__ out)                 // 3 regions of [M_][DIM_]
{
    __shared__ __hip_bfloat16 As[2][BM * BK];   // 2 x 32 KB
    __shared__ __hip_bfloat16 Bs[2][BN * BK];   // 2 x 32 KB

    // XCD L2-blocking: physical XCD = bid & 7 (round-robin dispatch).
    // XCD x owns tn in [3x, 3x+3): B working set = 3 panels = 3 MB (L2-fits).
    // Within the XCD, tn cycles fastest so 3 co-resident blocks share each
    // A panel fetch; A streams through L3 (64 MB total, L3-resident).
    int bid   = blockIdx.x;
    int x     = bid & 7;                     // XCD
    int local = bid >> 3;                    // 0..191
    int tn = x * 3 + local % 3;              // 0..23
    int tm = local / 3;                      // 0..63
    int m0 = tm * BM, n0 = tn * BN;

    int tid  = threadIdx.x;
    int lane = tid & 63;
    int w    = tid >> 6;                     // 0..7
    int wr   = w >> 2;                       // 0..1  row half (128 rows)
    int wc   = w & 3;                        // 0..3  col quarter (64 cols)

    // staging lane decomposition: 8 rows x 8 granules(16B) per wave-issue
    int rl   = lane >> 3;                    // row within 8
    int gsw  = ((lane & 7) ^ rl) * 8;        // pre-swizzled source col (elems)
    int lcol = (lane & 7) * 8;               // linear LDS col (elems)

    // fragment-read constants
    int fr = lane & 15;
    int fq = lane >> 4;                      // k granule within 32
    int l7 = lane & 7;
    int ce0 = ((0 + fq) ^ l7) * 8;           // swizzled col, kk=0
    int ce1 = ((4 + fq) ^ l7) * 8;           // swizzled col, kk=32

#define STAGE_A(t, bb, r) do {                                                 \
        const __hip_bfloat16* _s = Xb + (size_t)(m0 + (r) * 64 + w * 8 + rl) * K_ \
                                      + (t) * BK + gsw;                        \
        __hip_bfloat16* _d = &As[bb][((r) * 64 + w * 8 + rl) * BK + lcol];     \
        __builtin_amdgcn_global_load_lds(                                      \
            (const __attribute__((address_space(1))) void*)_s,                 \
            (__attribute__((address_space(3))) void*)_d, 16, 0, 0);            \
    } while (0)

#define STAGE_B(t, bb, r) do {                                                 \
        const __hip_bfloat16* _s = Wt + (size_t)(n0 + (r) * 64 + w * 8 + rl) * K_ \
                                      + (t) * BK + gsw;                        \
        __hip_bfloat16* _d = &Bs[bb][((r) * 64 + w * 8 + rl) * BK + lcol];     \
        __builtin_amdgcn_global_load_lds(                                      \
            (const __attribute__((address_space(1))) void*)_s,                 \
            (__attribute__((address_space(3))) void*)_d, 16, 0, 0);            \
    } while (0)

    f32x4  acc[2][2][4][2] = {};             // [qi][qj][i][j]
    bf16x8 a[4][2];                          // A frags for current qi
    bf16x8 b[2][2][2];                       // B frags [qj][j][kk]

#define LDA(bb, qi) do {                                                       \
        _Pragma("unroll")                                                      \
        for (int i = 0; i < 4; ++i) {                                          \
            int _row = wr * 128 + (qi) * 64 + i * 16 + fr;                     \
            a[i][0] = *reinterpret_cast<const bf16x8*>(&As[bb][_row * BK + ce0]); \
            a[i][1] = *reinterpret_cast<const bf16x8*>(&As[bb][_row * BK + ce1]); \
        }                                                                      \
    } while (0)

#define LDB(bb, qj) do {                                                       \
        _Pragma("unroll")                                                      \
        for (int j = 0; j < 2; ++j) {                                          \
            int _row = wc * 64 + (qj) * 32 + j * 16 + fr;                      \
            b[qj][j][0] = *reinterpret_cast<const bf16x8*>(&Bs[bb][_row * BK + ce0]); \
            b[qj][j][1] = *reinterpret_cast<const bf16x8*>(&Bs[bb][_row * BK + ce1]); \
        }                                                                      \
    } while (0)

#define MFMA_Q(qi, qj) do {                                                    \
        __builtin_amdgcn_s_setprio(1);                                         \
        _Pragma("unroll")                                                      \
        for (int i = 0; i < 4; ++i)                                            \
        _Pragma("unroll")                                                      \
        for (int j = 0; j < 2; ++j) {                                          \
            acc[qi][qj][i][j] = __builtin_amdgcn_mfma_f32_16x16x32_bf16(       \
                a[i][0], b[qj][j][0], acc[qi][qj][i][j], 0, 0, 0);             \
            acc[qi][qj][i][j] = __builtin_amdgcn_mfma_f32_16x16x32_bf16(       \
                a[i][1], b[qj][j][1], acc[qi][qj][i][j], 0, 0, 0);             \
        }                                                                      \
        __builtin_amdgcn_s_setprio(0);                                         \
    } while (0)

    // -------- prologue: A(0)->buf0, B(0)->buf0, B(1)->buf1 ------------------
#pragma unroll
    for (int r = 0; r < 4; ++r) STAGE_A(0, 0, r);
#pragma unroll
    for (int r = 0; r < 4; ++r) STAGE_B(0, 0, r);
#pragma unroll
    for (int r = 0; r < 4; ++r) STAGE_B(1, 1, r);
    WAIT_VM(4);                              // A(0),B(0) landed; B(1) in flight
    BAR();

    // -------- main loop: 8 phases / 2 K-tiles (R3 schedule, unchanged) -----
    for (int u = 0; u < NU; ++u) {
        int T0 = 2 * u, T1 = 2 * u + 1;
        bool last = (u == NU - 1);
        // ph1: T0 quad (0,0)
        LDA(0, 0); LDB(0, 0);
        STAGE_A(T1, 1, 0); STAGE_A(T1, 1, 1);
        LGKM8();
        BAR(); LGKM0();
        MFMA_Q(0, 0);
        BAR();
        // ph2: T0 quad (0,1)
        LDB(0, 1);
        STAGE_A(T1, 1, 2); STAGE_A(T1, 1, 3);
        BAR(); LGKM0();
        MFMA_Q(0, 1);
        BAR();
        // ph3: T0 quad (1,0)
        LDA(0, 1);
        if (!last) { STAGE_B(T0 + 2, 0, 0); STAGE_B(T0 + 2, 0, 1); }
        BAR(); LGKM0();
        MFMA_Q(1, 0);
        BAR();
        // ph4: T0 quad (1,1)
        if (!last) { STAGE_A(T0 + 2, 0, 0); STAGE_A(T0 + 2, 0, 1); }
        BAR();
        MFMA_Q(1, 1);
        if (last) { WAIT_VM(0); } else { WAIT_VM(4); }
        BAR();
        // ph5: T1 quad (0,0)
        LDA(1, 0); LDB(1, 0);
        if (!last) { STAGE_A(T0 + 2, 0, 2); STAGE_A(T0 + 2, 0, 3); }
        LGKM8();
        BAR(); LGKM0();
        MFMA_Q(0, 0);
        BAR();
        // ph6: T1 quad (0,1)
        LDB(1, 1);
        if (!last) { STAGE_B(T0 + 2, 0, 2); STAGE_B(T0 + 2, 0, 3); }
        BAR(); LGKM0();
        MFMA_Q(0, 1);
        BAR();
        // ph7: T1 quad (1,0)
        LDA(1, 1);
        if (!last) { STAGE_B(T1 + 2, 1, 0); STAGE_B(T1 + 2, 1, 1); }
        BAR(); LGKM0();
        MFMA_Q(1, 0);
        BAR();
        // ph8: T1 quad (1,1)
        if (!last) { STAGE_B(T1 + 2, 1, 2); STAGE_B(T1 + 2, 1, 3); }
        BAR();
        MFMA_Q(1, 1);
        if (!last) { WAIT_VM(4); }
        BAR();
    }

    // -------- epilogue: RoPE + nontemporal store ----------------------------
    // C/D layout (16x16): col = lane&15 (=fr), row = (lane>>4)*4 + r
#pragma unroll
    for (int qi = 0; qi < 2; ++qi)
#pragma unroll
    for (int i = 0; i < 4; ++i) {
        int mbase = m0 + wr * 128 + qi * 64 + i * 16 + fq * 4;
#pragma unroll
        for (int qj = 0; qj < 2; ++qj)
#pragma unroll
        for (int j = 0; j < 2; ++j) {
            int n = n0 + wc * 64 + qj * 32 + j * 16 + fr;
            int region = n >> 11;            // 0=q,1=k,2=v
            int cc = n & (DIM_ - 1);
            int d  = cc & (HD_ - 1);
#pragma unroll
            for (int r = 0; r < 4; ++r) {
                int m = mbase + r;
                int s = m & (S_ - 1);
                float g  = acc[qi][qj][i][j][r];
                float gp = __shfl_xor(g, 1, 64);  // interleaved pair partner
                float o;
                if (region < 2) {
                    float cv = fcos[s * HD_ + d];
                    float sv = fsin[s * HD_ + d];
                    o = g * cv + ((cc & 1) ? gp * sv : -gp * sv);
                } else {
                    o = g;
                }
                __builtin_nontemporal_store(
                    o, &out[(size_t)region * M_ * DIM_ + (size_t)m * DIM_ + cc]);
            }
        }
    }
#undef STAGE_A
#undef STAGE_B
#undef LDA
#undef LDB
#undef MFMA_Q
}

// ---------------------------------------------------------------------------
extern "C" void kernel_launch(void* const* d_in, const int* in_sizes, int n_in,
                              void* d_out, int out_size, void* d_ws, size_t ws_size,
                              hipStream_t stream) {
    const float* X    = (const float*)d_in[0];
    const float* fcos = (const float*)d_in[1];
    const float* fsin = (const float*)d_in[2];
    // d_in[3] = attention_mask (all ones, unused by the reference math)
    const float* Wq   = (const float*)d_in[4];
    const float* Wk   = (const float*)d_in[5];
    const float* Wv   = (const float*)d_in[6];
    float* out = (float*)d_out;

    __hip_bfloat16* Xb  = (__hip_bfloat16*)d_ws;
    __hip_bfloat16* Wtp = Xb + (size_t)M_ * K_;

    {
        int threads = 256;
        int blocks = (M_ * K_) / (threads * 8);   // 16384
        cvt_x_kernel<<<blocks, threads, 0, stream>>>(X, Xb);
    }
    {
        dim3 grid(DIM_ / 32, DIM_ / 32, 3);
        dim3 block(32, 8);
        cvt_w_kernel<<<grid, block, 0, stream>>>(Wq, Wk, Wv, Wtp);
    }
    {
        int blocks = (M_ / BM) * (N_ / BN);       // 64 * 24 = 1536
        gemm_rope_kernel<<<blocks, 512, 0, stream>>>(Xb, Wtp, fcos, fsin, out);
    }
}

// Round 6
// 531.002 us; speedup vs baseline: 1.2695x; 1.0129x over previous
//
#include <hip/hip_runtime.h>
#include <hip/hip_bf16.h>
#include <stdint.h>

// Problem constants
#define B_    4
#define S_    4096
#define DIM_  2048
#define H_    16
#define HD_   128
#define M_    (B_ * S_)     // 16384 rows
#define K_    DIM_          // 2048
#define N_    (3 * DIM_)    // 6144 (q|k|v concatenated)

typedef __attribute__((ext_vector_type(8))) short bf16x8;
typedef __attribute__((ext_vector_type(4))) float f32x4;

// ---------------------------------------------------------------------------
// Kernel 1: X fp32 -> bf16
// ---------------------------------------------------------------------------
__global__ void cvt_x_kernel(const float* __restrict__ X,
                             __hip_bfloat16* __restrict__ Xb) {
    size_t i = ((size_t)blockIdx.x * 256 + threadIdx.x) * 8;
    float4 a = *reinterpret_cast<const float4*>(X + i);
    float4 b = *reinterpret_cast<const float4*>(X + i + 4);
    union { __hip_bfloat16 h[8]; uint4 u; } o;
    o.h[0] = __float2bfloat16(a.x);
    o.h[1] = __float2bfloat16(a.y);
    o.h[2] = __float2bfloat16(a.z);
    o.h[3] = __float2bfloat16(a.w);
    o.h[4] = __float2bfloat16(b.x);
    o.h[5] = __float2bfloat16(b.y);
    o.h[6] = __float2bfloat16(b.z);
    o.h[7] = __float2bfloat16(b.w);
    *reinterpret_cast<uint4*>(Xb + i) = o.u;
}

// ---------------------------------------------------------------------------
// Kernel 2: Wt[n][k] = W_sel[k][n] cast to bf16  (B^T layout)
// ---------------------------------------------------------------------------
__global__ void cvt_w_kernel(const float* __restrict__ Wq,
                             const float* __restrict__ Wk,
                             const float* __restrict__ Wv,
                             __hip_bfloat16* __restrict__ Wt) {
    __shared__ float tile[32][33];
    int w = blockIdx.z;
    const float* W = (w == 0) ? Wq : (w == 1) ? Wk : Wv;
    int n0 = blockIdx.x * 32;
    int k0 = blockIdx.y * 32;
    int tx = threadIdx.x, ty = threadIdx.y;
#pragma unroll
    for (int r = 0; r < 4; ++r) {
        int k = k0 + ty + r * 8;
        tile[ty + r * 8][tx] = W[(size_t)k * DIM_ + n0 + tx];
    }
    __syncthreads();
#pragma unroll
    for (int r = 0; r < 4; ++r) {
        int n = n0 + ty + r * 8;
        Wt[(size_t)(w * DIM_ + n) * K_ + k0 + tx] =
            __float2bfloat16(tile[tx][ty + r * 8]);
    }
}

// ---------------------------------------------------------------------------
// Kernel 3: 256x256 8-phase bf16 GEMM (16x16x32 MFMA) + RoPE.
// Changes vs R5: removed explicit lgkmcnt(0) drains — compiler emits
// fine-grained per-MFMA lgkm waits; safety: every phase's ds_reads are
// consumed by that phase's MFMA cluster before the phase-end barrier.
// ---------------------------------------------------------------------------
#define BM 256
#define BN 256
#define BK 64
#define NT (K_ / BK)    // 32
#define NU (NT / 2)     // 16 iterations, 2 K-tiles each

#define BAR()      asm volatile("s_barrier" ::: "memory")
#define LGKM8()    asm volatile("s_waitcnt lgkmcnt(8)" ::: "memory")
#define WAIT_VM(n) asm volatile("s_waitcnt vmcnt(" #n ")" ::: "memory")

__global__ __launch_bounds__(512, 1) void gemm_rope_kernel(
    const __hip_bfloat16* __restrict__ Xb,   // [M_][K_]
    const __hip_bfloat16* __restrict__ Wt,   // [N_][K_]
    const float* __restrict__ fcos,          // [S_][HD_]
    const float* __restrict__ fsin,          // [S_][HD_]
    float* __restrict__ out)                 // 3 regions of [M_][DIM_]
{
    __shared__ __hip_bfloat16 As[2][BM * BK];   // 2 x 32 KB
    __shared__ __hip_bfloat16 Bs[2][BN * BK];   // 2 x 32 KB

    // XCD L2-blocking: XCD x owns tn in [3x, 3x+3) -> 3 MB B set L2-resident.
    int bid   = blockIdx.x;
    int x     = bid & 7;                     // XCD
    int local = bid >> 3;                    // 0..191
    int tn = x * 3 + local % 3;              // 0..23
    int tm = local / 3;                      // 0..63
    int m0 = tm * BM, n0 = tn * BN;

    int tid  = threadIdx.x;
    int lane = tid & 63;
    int w    = tid >> 6;                     // 0..7
    int wr   = w >> 2;                       // 0..1  row half (128 rows)
    int wc   = w & 3;                        // 0..3  col quarter (64 cols)

    // staging lane decomposition: 8 rows x 8 granules(16B) per wave-issue
    int rl   = lane >> 3;                    // row within 8
    int gsw  = ((lane & 7) ^ rl) * 8;        // pre-swizzled source col (elems)
    int lcol = (lane & 7) * 8;               // linear LDS col (elems)

    // fragment-read constants
    int fr = lane & 15;
    int fq = lane >> 4;                      // k granule within 32
    int l7 = lane & 7;
    int ce0 = ((0 + fq) ^ l7) * 8;           // swizzled col, kk=0
    int ce1 = ((4 + fq) ^ l7) * 8;           // swizzled col, kk=32

#define STAGE_A(t, bb, r) do {                                                 \
        const __hip_bfloat16* _s = Xb + (size_t)(m0 + (r) * 64 + w * 8 + rl) * K_ \
                                      + (t) * BK + gsw;                        \
        __hip_bfloat16* _d = &As[bb][((r) * 64 + w * 8 + rl) * BK + lcol];     \
        __builtin_amdgcn_global_load_lds(                                      \
            (const __attribute__((address_space(1))) void*)_s,                 \
            (__attribute__((address_space(3))) void*)_d, 16, 0, 0);            \
    } while (0)

#define STAGE_B(t, bb, r) do {                                                 \
        const __hip_bfloat16* _s = Wt + (size_t)(n0 + (r) * 64 + w * 8 + rl) * K_ \
                                      + (t) * BK + gsw;                        \
        __hip_bfloat16* _d = &Bs[bb][((r) * 64 + w * 8 + rl) * BK + lcol];     \
        __builtin_amdgcn_global_load_lds(                                      \
            (const __attribute__((address_space(1))) void*)_s,                 \
            (__attribute__((address_space(3))) void*)_d, 16, 0, 0);            \
    } while (0)

    f32x4  acc[2][2][4][2] = {};             // [qi][qj][i][j]
    bf16x8 a[4][2];                          // A frags for current qi
    bf16x8 b[2][2][2];                       // B frags [qj][j][kk]

#define LDA(bb, qi) do {                                                       \
        _Pragma("unroll")                                                      \
        for (int i = 0; i < 4; ++i) {                                          \
            int _row = wr * 128 + (qi) * 64 + i * 16 + fr;                     \
            a[i][0] = *reinterpret_cast<const bf16x8*>(&As[bb][_row * BK + ce0]); \
            a[i][1] = *reinterpret_cast<const bf16x8*>(&As[bb][_row * BK + ce1]); \
        }                                                                      \
    } while (0)

#define LDB(bb, qj) do {                                                       \
        _Pragma("unroll")                                                      \
        for (int j = 0; j < 2; ++j) {                                          \
            int _row = wc * 64 + (qj) * 32 + j * 16 + fr;                      \
            b[qj][j][0] = *reinterpret_cast<const bf16x8*>(&Bs[bb][_row * BK + ce0]); \
            b[qj][j][1] = *reinterpret_cast<const bf16x8*>(&Bs[bb][_row * BK + ce1]); \
        }                                                                      \
    } while (0)

#define MFMA_Q(qi, qj) do {                                                    \
        __builtin_amdgcn_s_setprio(1);                                         \
        _Pragma("unroll")                                                      \
        for (int i = 0; i < 4; ++i)                                            \
        _Pragma("unroll")                                                      \
        for (int j = 0; j < 2; ++j) {                                          \
            acc[qi][qj][i][j] = __builtin_amdgcn_mfma_f32_16x16x32_bf16(       \
                a[i][0], b[qj][j][0], acc[qi][qj][i][j], 0, 0, 0);             \
            acc[qi][qj][i][j] = __builtin_amdgcn_mfma_f32_16x16x32_bf16(       \
                a[i][1], b[qj][j][1], acc[qi][qj][i][j], 0, 0, 0);             \
        }                                                                      \
        __builtin_amdgcn_s_setprio(0);                                         \
    } while (0)

    // -------- prologue: A(0)->buf0, B(0)->buf0, B(1)->buf1 ------------------
#pragma unroll
    for (int r = 0; r < 4; ++r) STAGE_A(0, 0, r);
#pragma unroll
    for (int r = 0; r < 4; ++r) STAGE_B(0, 0, r);
#pragma unroll
    for (int r = 0; r < 4; ++r) STAGE_B(1, 1, r);
    WAIT_VM(4);                              // A(0),B(0) landed; B(1) in flight
    BAR();

    // -------- main loop: 8 phases / 2 K-tiles -------------------------------
    for (int u = 0; u < NU; ++u) {
        int T0 = 2 * u, T1 = 2 * u + 1;
        bool last = (u == NU - 1);
        // ph1: T0 quad (0,0)
        LDA(0, 0); LDB(0, 0);
        STAGE_A(T1, 1, 0); STAGE_A(T1, 1, 1);
        LGKM8();
        BAR();
        MFMA_Q(0, 0);
        BAR();
        // ph2: T0 quad (0,1)
        LDB(0, 1);
        STAGE_A(T1, 1, 2); STAGE_A(T1, 1, 3);
        BAR();
        MFMA_Q(0, 1);
        BAR();
        // ph3: T0 quad (1,0)
        LDA(0, 1);
        if (!last) { STAGE_B(T0 + 2, 0, 0); STAGE_B(T0 + 2, 0, 1); }
        BAR();
        MFMA_Q(1, 0);
        BAR();
        // ph4: T0 quad (1,1)
        if (!last) { STAGE_A(T0 + 2, 0, 0); STAGE_A(T0 + 2, 0, 1); }
        BAR();
        MFMA_Q(1, 1);
        if (last) { WAIT_VM(0); } else { WAIT_VM(4); }
        BAR();
        // ph5: T1 quad (0,0)
        LDA(1, 0); LDB(1, 0);
        if (!last) { STAGE_A(T0 + 2, 0, 2); STAGE_A(T0 + 2, 0, 3); }
        LGKM8();
        BAR();
        MFMA_Q(0, 0);
        BAR();
        // ph6: T1 quad (0,1)
        LDB(1, 1);
        if (!last) { STAGE_B(T0 + 2, 0, 2); STAGE_B(T0 + 2, 0, 3); }
        BAR();
        MFMA_Q(0, 1);
        BAR();
        // ph7: T1 quad (1,0)
        LDA(1, 1);
        if (!last) { STAGE_B(T1 + 2, 1, 0); STAGE_B(T1 + 2, 1, 1); }
        BAR();
        MFMA_Q(1, 0);
        BAR();
        // ph8: T1 quad (1,1)
        if (!last) { STAGE_B(T1 + 2, 1, 2); STAGE_B(T1 + 2, 1, 3); }
        BAR();
        MFMA_Q(1, 1);
        if (!last) { WAIT_VM(4); }
        BAR();
    }

    // -------- epilogue: RoPE + nontemporal store ----------------------------
    // C/D layout (16x16): col = lane&15 (=fr), row = (lane>>4)*4 + r
#pragma unroll
    for (int qi = 0; qi < 2; ++qi)
#pragma unroll
    for (int i = 0; i < 4; ++i) {
        int mbase = m0 + wr * 128 + qi * 64 + i * 16 + fq * 4;
#pragma unroll
        for (int qj = 0; qj < 2; ++qj)
#pragma unroll
        for (int j = 0; j < 2; ++j) {
            int n = n0 + wc * 64 + qj * 32 + j * 16 + fr;
            int region = n >> 11;            // 0=q,1=k,2=v
            int cc = n & (DIM_ - 1);
            int d  = cc & (HD_ - 1);
#pragma unroll
            for (int r = 0; r < 4; ++r) {
                int m = mbase + r;
                int s = m & (S_ - 1);
                float g  = acc[qi][qj][i][j][r];
                float gp = __shfl_xor(g, 1, 64);  // interleaved pair partner
                float o;
                if (region < 2) {
                    float cv = fcos[s * HD_ + d];
                    float sv = fsin[s * HD_ + d];
                    o = g * cv + ((cc & 1) ? gp * sv : -gp * sv);
                } else {
                    o = g;
                }
                __builtin_nontemporal_store(
                    o, &out[(size_t)region * M_ * DIM_ + (size_t)m * DIM_ + cc]);
            }
        }
    }
#undef STAGE_A
#undef STAGE_B
#undef LDA
#undef LDB
#undef MFMA_Q
}

// ---------------------------------------------------------------------------
extern "C" void kernel_launch(void* const* d_in, const int* in_sizes, int n_in,
                              void* d_out, int out_size, void* d_ws, size_t ws_size,
                              hipStream_t stream) {
    const float* X    = (const float*)d_in[0];
    const float* fcos = (const float*)d_in[1];
    const float* fsin = (const float*)d_in[2];
    // d_in[3] = attention_mask (all ones, unused by the reference math)
    const float* Wq   = (const float*)d_in[4];
    const float* Wk   = (const float*)d_in[5];
    const float* Wv   = (const float*)d_in[6];
    float* out = (float*)d_out;

    __hip_bfloat16* Xb  = (__hip_bfloat16*)d_ws;
    __hip_bfloat16* Wtp = Xb + (size_t)M_ * K_;

    {
        int threads = 256;
        int blocks = (M_ * K_) / (threads * 8);   // 16384
        cvt_x_kernel<<<blocks, threads, 0, stream>>>(X, Xb);
    }
    {
        dim3 grid(DIM_ / 32, DIM_ / 32, 3);
        dim3 block(32, 8);
        cvt_w_kernel<<<grid, block, 0, stream>>>(Wq, Wk, Wv, Wtp);
    }
    {
        int blocks = (M_ / BM) * (N_ / BN);       // 64 * 24 = 1536
        gemm_rope_kernel<<<blocks, 512, 0, stream>>>(Xb, Wtp, fcos, fsin, out);
    }
}